// Round 10
// baseline (204.407 us; speedup 1.0000x reference)
//
#include <hip/hip_runtime.h>
#include <hip/hip_bf16.h>

#define BF16 __hip_bfloat16

typedef __bf16 bf16x8 __attribute__((ext_vector_type(8)));
typedef float floatx4 __attribute__((ext_vector_type(4)));

typedef const __attribute__((address_space(1))) void GV;
typedef __attribute__((address_space(3))) void LV;
// async global->LDS, 16B per lane; LDS dest must be wave-uniform base + lane*16
#define GLD16(gp, lp) __builtin_amdgcn_global_load_lds((GV*)(gp), (LV*)(lp), 16, 0, 0)

// ---------------- features transpose + fp32->bf16 (roi_align's only dep) ----
__global__ __launch_bounds__(256) void t_feat(const float* __restrict__ features,
                                              BF16* __restrict__ featT) {
    __shared__ float tile[64][33];
    int bid = blockIdx.x;                   // 2 x [256][13600]: 4 x 425 tiles each
    int z = bid / 1700, r = bid - z * 1700;
    int cx = r % 425, cy = r / 425;
    const int R = 256, C = 13600;
    const float* ip = features + (size_t)z * 256 * 13600;
    BF16* op = featT + (size_t)z * 256 * 13600;

    int tx = threadIdx.x & 31, ty = threadIdx.x >> 5;
    int r0 = cy << 6, c0 = cx << 5;
#pragma unroll
    for (int i = 0; i < 8; ++i)
        tile[ty + i * 8][tx] = ip[(size_t)(r0 + ty + i * 8) * C + c0 + tx];
    __syncthreads();
#pragma unroll
    for (int i = 0; i < 4; ++i) {
        int c = ty + i * 8;
        BF16 a = __float2bfloat16(tile[tx * 2][c]);       // 2-way LDS alias: free
        BF16 b = __float2bfloat16(tile[tx * 2 + 1][c]);
        unsigned int pk = (unsigned int)*(unsigned short*)&a |
                          ((unsigned int)*(unsigned short*)&b << 16);
        *(unsigned int*)(op + (size_t)(c0 + c) * R + r0 + tx * 2) = pk;
    }
}

// -------- ROI align (2 channel-half passes, 18.8 KB LDS) + weight transposes ----
// blocks 0..1023: ROI; blocks 1024..7807: wt. At 18.8 KB the CU holds 8 blocks
// (the 32-wave cap) -> 1024 roi + 1024 wt RESIDENT FROM t=0: wt's 83 MB of
// HBM streaming hides under the L2-latency-bound ROI gather instead of
// running serially after it (r6/r8 evidence: ROI phase ~30us is independent
// of roi-block count; wt was serialized only by slot starvation).
// ROI: pass h gathers channels [128h,128h+128) into lbuf[128][49], then bulk
// uint4-copies to feats[roi][h*6272..]. Tap bytes unchanged (each half loads
// only its own 128 channels).
__global__ __launch_bounds__(256) void roi_and_wt(const BF16* __restrict__ featT,
                                                  const float* __restrict__ boxes,
                                                  const int* __restrict__ roi_batch,
                                                  BF16* __restrict__ feats,
                                                  const float* __restrict__ fc1_w,
                                                  const float* __restrict__ fc2_w,
                                                  BF16* __restrict__ w1t,
                                                  BF16* __restrict__ w2t) {
    __shared__ __align__(16) char smem[18816];   // union: roi(18816) | transpose(8448)
    int bid = blockIdx.x;
    int t = threadIdx.x;

    if (bid >= 1024) {
        // ---- weight transpose branch (64x32 tile, same as t_feat) ----
        float (*tile)[33] = (float(*)[33])smem;
        int r = bid - 1024;
        const float* ip;
        BF16* op;
        int R, C, cx, cy;
        if (r < 6272) {                     // fc1_w: [12544][1024], 196 x 32 tiles
            cx = r & 31; cy = r >> 5;
            R = 12544; C = 1024;
            ip = fc1_w; op = w1t;
        } else {                            // fc2_w: [1024][1024], 16 x 32 tiles
            r -= 6272;
            cx = r & 31; cy = r >> 5;
            R = 1024; C = 1024;
            ip = fc2_w; op = w2t;
        }
        int tx = t & 31, ty = t >> 5;
        int r0 = cy << 6, c0 = cx << 5;
#pragma unroll
        for (int i = 0; i < 8; ++i)
            tile[ty + i * 8][tx] = ip[(size_t)(r0 + ty + i * 8) * C + c0 + tx];
        __syncthreads();
#pragma unroll
        for (int i = 0; i < 4; ++i) {
            int c = ty + i * 8;
            BF16 a = __float2bfloat16(tile[tx * 2][c]);
            BF16 b = __float2bfloat16(tile[tx * 2 + 1][c]);
            unsigned int pk = (unsigned int)*(unsigned short*)&a |
                              ((unsigned int)*(unsigned short*)&b << 16);
            *(unsigned int*)(op + (size_t)(c0 + c) * R + r0 + tx * 2) = pk;
        }
        return;
    }

    // ---- ROI align branch (two channel-half passes) ----
    int   (*s_off)[4] = (int(*)[4])smem;            // [196][4] = 3136 B
    float (*s_w)[4]   = (float(*)[4])(smem + 3136); // [196][4] = 3136 B
    BF16* lbuf        = (BF16*)(smem + 6272);       // [128][49] bf16 = 12544 B

    int roi = bid;
    BF16* orow = feats + (size_t)roi * 12544;
    if (roi >= 1000) {
        uint4* o4 = (uint4*)orow;
        uint4 z = {0u, 0u, 0u, 0u};
        for (int i = t; i < 1568; i += 256) o4[i] = z;
        return;
    }
    int b = roi_batch[roi];

    if (t < 196) {
        float x1 = boxes[roi * 4 + 0] * 0.125f;
        float y1 = boxes[roi * 4 + 1] * 0.125f;
        float x2 = boxes[roi * 4 + 2] * 0.125f;
        float y2 = boxes[roi * 4 + 3] * 0.125f;
        float bw = fmaxf(x2 - x1, 1.0f) * (1.0f / 7.0f);
        float bh = fmaxf(y2 - y1, 1.0f) * (1.0f / 7.0f);
        int cell = t >> 2, s = t & 3;
        int oy = cell / 7, ox = cell - oy * 7;
        int sy = s >> 1, sx = s & 1;
        float yc = y1 + ((float)oy + ((float)sy + 0.5f) * 0.5f) * bh;
        float xc = x1 + ((float)ox + ((float)sx + 0.5f) * 0.5f) * bw;
        yc = fminf(fmaxf(yc, 0.0f), 99.0f);
        xc = fminf(fmaxf(xc, 0.0f), 135.0f);
        float y0f = floorf(yc), x0f = floorf(xc);
        int y0 = (int)y0f, x0 = (int)x0f;
        int y1i = min(y0 + 1, 99), x1i = min(x0 + 1, 135);
        float ly = yc - y0f, lx = xc - x0f;
        s_w[t][0] = (1.0f - ly) * (1.0f - lx) * 0.25f;
        s_w[t][1] = (1.0f - ly) * lx * 0.25f;
        s_w[t][2] = ly * (1.0f - lx) * 0.25f;
        s_w[t][3] = ly * lx * 0.25f;
        s_off[t][0] = (y0 * 136 + x0) * 256;
        s_off[t][1] = (y0 * 136 + x1i) * 256;
        s_off[t][2] = (y1i * 136 + x0) * 256;
        s_off[t][3] = (y1i * 136 + x1i) * 256;
    }
    __syncthreads();

    int cb = t & 15, g = t >> 4;   // 16 ch-blocks x 8ch; 16 cell groups
    int chbase = cb * 8;
#pragma unroll
    for (int h = 0; h < 2; ++h) {
        const BF16* fb = featT + (size_t)b * (100 * 136 * 256) + h * 128 + cb * 8;
        for (int cell = g; cell < 49; cell += 16) {
            float a[8];
#pragma unroll
            for (int j = 0; j < 8; ++j) a[j] = 0.0f;
#pragma unroll
            for (int s = 0; s < 4; ++s) {
                int p = cell * 4 + s;
#pragma unroll
                for (int tap = 0; tap < 4; ++tap) {
                    float w = s_w[p][tap];
                    bf16x8 v = *(const bf16x8*)(fb + s_off[p][tap]);
#pragma unroll
                    for (int j = 0; j < 8; ++j) a[j] += w * (float)v[j];
                }
            }
#pragma unroll
            for (int j = 0; j < 8; ++j)
                lbuf[(chbase + j) * 49 + cell] = __float2bfloat16(a[j]);
        }
        __syncthreads();                       // all lbuf writes done
        uint4* o4 = (uint4*)(orow + h * 6272);
        const uint4* l4 = (const uint4*)lbuf;
        for (int i = t; i < 784; i += 256) o4[i] = l4[i];
        if (h == 0) __syncthreads();           // copy done before lbuf reuse
    }
}

// ---- split-K bf16 MFMA GEMM, 128x128 tile, BK=64 ----
// 2-buffer (64 KiB) counted-vmcnt pipeline (round-5 proven). XCD-chunked
// swizzle (proved FETCH 113 -> 50 MB). vmcnt never drains to 0 until the tail.
#define STAGE_TILE(kbi, bj)                                                     \
    do {                                                                        \
        size_t ko_ = (size_t)(kbi) * 128;                                       \
        _Pragma("unroll")                                                       \
        for (int i_ = 0; i_ < 4; ++i_) {                                        \
            GLD16(gA + (size_t)(i_ * 8) * strideA + ko_,                        \
                  &lds[bj][0][lw + i_ * 1024]);                                 \
            GLD16(gB + (size_t)(i_ * 8) * strideA + ko_,                        \
                  &lds[bj][1][lw + i_ * 1024]);                                 \
        }                                                                       \
    } while (0)

__global__ __launch_bounds__(256) void gemm_splitk(const BF16* __restrict__ A,
                                                   const BF16* __restrict__ Bt,
                                                   float* __restrict__ P,
                                                   int K, int chunk) {
    __shared__ char lds[2][2][16384];   // 64 KB: 2 buffers x (A,B)
    int b = blockIdx.x;
    int L = (b & 7) * (gridDim.x >> 3) + (b >> 3);   // XCD-chunked, bijective (nwg%8==0)
    int tn = L & 7, tm = (L >> 3) & 7, s = L >> 6;

    int w = threadIdx.x >> 6, l = threadIdx.x & 63;
    int wm = w & 1, wn = w >> 1;
    int k0 = s * chunk;

    floatx4 acc[4][4];
#pragma unroll
    for (int i = 0; i < 4; ++i)
#pragma unroll
        for (int j = 0; j < 4; ++j) acc[i][j] = (floatx4){0.f, 0.f, 0.f, 0.f};

    const size_t strideA = (size_t)K * 2;
    int r8 = l >> 3;
    int g8 = (l & 7) ^ r8;       // XOR-swizzled global chunk for this lane
    const char* gA = (const char*)A + (size_t)(tm * 128 + w * 32 + r8) * strideA
                     + (size_t)k0 * 2 + (size_t)g8 * 16;
    const char* gB = (const char*)Bt + (size_t)(tn * 128 + w * 32 + r8) * strideA
                     + (size_t)k0 * 2 + (size_t)g8 * 16;
    int lw = w * 4096 + l * 16;  // wave-uniform base + l*16: gload_lds layout

    int c = l & 15, q = l >> 4;
    int xa0 = ((0 * 4 + q) ^ (c & 7)) * 16;
    int xa1 = ((1 * 4 + q) ^ (c & 7)) * 16;
    int abase = (wm * 64 + c) * 128;
    int bbase = (wn * 64 + c) * 128;

    int nIter = chunk >> 6;

    STAGE_TILE(0, 0);

    for (int kb = 0; kb < nIter; ++kb) {
        int cur = kb & 1;
        if (kb + 1 < nIter) {
            STAGE_TILE(kb + 1, cur ^ 1);   // ordered after prev reads by barrier #2
            asm volatile("s_waitcnt vmcnt(8)" ::: "memory");   // stage(kb) landed
        } else {
            asm volatile("s_waitcnt vmcnt(0)" ::: "memory");
        }
        __builtin_amdgcn_sched_barrier(0);
        __builtin_amdgcn_s_barrier();      // all waves' stage(kb) landed
        __builtin_amdgcn_sched_barrier(0);

        const char* bufA = lds[cur][0];
        const char* bufB = lds[cur][1];
#pragma unroll
        for (int kk = 0; kk < 2; ++kk) {
            int xo = kk ? xa1 : xa0;
            bf16x8 af[4], bfr[4];
#pragma unroll
            for (int mi = 0; mi < 4; ++mi) af[mi] = *(const bf16x8*)(bufA + abase + mi * 2048 + xo);
#pragma unroll
            for (int ni = 0; ni < 4; ++ni) bfr[ni] = *(const bf16x8*)(bufB + bbase + ni * 2048 + xo);
#pragma unroll
            for (int mi = 0; mi < 4; ++mi)
#pragma unroll
                for (int ni = 0; ni < 4; ++ni)
                    acc[mi][ni] = __builtin_amdgcn_mfma_f32_16x16x32_bf16(af[mi], bfr[ni], acc[mi][ni], 0, 0, 0);
        }
        __builtin_amdgcn_sched_barrier(0);
        __builtin_amdgcn_s_barrier();      // reads of buf[cur] done before restage
    }

    size_t base = (size_t)s << 20;
#pragma unroll
    for (int mi = 0; mi < 4; ++mi) {
        int rowG = tm * 128 + wm * 64 + mi * 16 + q * 4;
#pragma unroll
        for (int ni = 0; ni < 4; ++ni) {
            int colG = tn * 128 + wn * 64 + ni * 16 + c;
#pragma unroll
            for (int r = 0; r < 4; ++r)
                P[base + (size_t)(rowG + r) * 1024 + colG] = acc[mi][ni][r];
        }
    }
}

// ---- fc2 GEMM: 64x64 tile, full K=1024, 256 blocks (1/CU), bias+ReLU ----
// (round-9 proven: +4-6us vs 64-block version)
#define STAGE64(kbi, bj)                                                        \
    do {                                                                        \
        size_t ko_ = (size_t)(kbi) * 128;                                       \
        _Pragma("unroll")                                                       \
        for (int i_ = 0; i_ < 2; ++i_) {                                        \
            GLD16(gA + (size_t)(i_ * 8) * strideA + ko_,                        \
                  &lds[bj][0][lw64 + i_ * 1024]);                               \
            GLD16(gB + (size_t)(i_ * 8) * strideA + ko_,                        \
                  &lds[bj][1][lw64 + i_ * 1024]);                               \
        }                                                                       \
    } while (0)

__global__ __launch_bounds__(256) void gemm_fc2(const BF16* __restrict__ A,
                                                const BF16* __restrict__ Bt,
                                                const float* __restrict__ bias,
                                                float* __restrict__ H) {
    __shared__ char lds[2][2][8192];    // 32 KB: 2 bufs x (A 64x64, B 64x64)
    int b = blockIdx.x;
    int L = (b & 7) * 32 + (b >> 3);    // XCD-chunked, 256 % 8 == 0
    int tn = L & 15, tm = L >> 4;       // 16 x 16 tiles of 64x64

    int w = threadIdx.x >> 6, l = threadIdx.x & 63;
    int wm = w & 1, wn = w >> 1;        // wave quadrant: 32x32 out each

    floatx4 acc[2][2];
#pragma unroll
    for (int i = 0; i < 2; ++i)
#pragma unroll
        for (int j = 0; j < 2; ++j) acc[i][j] = (floatx4){0.f, 0.f, 0.f, 0.f};

    const size_t strideA = 2048;   // K=1024 bf16
    int r8 = l >> 3;
    int g8 = (l & 7) ^ r8;         // XOR swizzle on global source chunk
    const char* gA = (const char*)A + (size_t)(tm * 64 + w * 16 + r8) * strideA
                     + (size_t)g8 * 16;
    const char* gB = (const char*)Bt + (size_t)(tn * 64 + w * 16 + r8) * strideA
                     + (size_t)g8 * 16;
    int lw64 = w * 2048 + l * 16;

    int c = l & 15, q = l >> 4;
    int xa0 = ((0 * 4 + q) ^ (c & 7)) * 16;
    int xa1 = ((1 * 4 + q) ^ (c & 7)) * 16;
    int abase = (wm * 32 + c) * 128;
    int bbase = (wn * 32 + c) * 128;

    const int nIter = 16;   // 1024 / 64

    STAGE64(0, 0);

    for (int kb = 0; kb < nIter; ++kb) {
        int cur = kb & 1;
        if (kb + 1 < nIter) {
            STAGE64(kb + 1, cur ^ 1);
            asm volatile("s_waitcnt vmcnt(4)" ::: "memory");   // stage(kb) landed
        } else {
            asm volatile("s_waitcnt vmcnt(0)" ::: "memory");
        }
        __builtin_amdgcn_sched_barrier(0);
        __builtin_amdgcn_s_barrier();
        __builtin_amdgcn_sched_barrier(0);

        const char* bufA = lds[cur][0];
        const char* bufB = lds[cur][1];
#pragma unroll
        for (int kk = 0; kk < 2; ++kk) {
            int xo = kk ? xa1 : xa0;
            bf16x8 af[2], bfr[2];
#pragma unroll
            for (int mi = 0; mi < 2; ++mi) af[mi] = *(const bf16x8*)(bufA + abase + mi * 2048 + xo);
#pragma unroll
            for (int ni = 0; ni < 2; ++ni) bfr[ni] = *(const bf16x8*)(bufB + bbase + ni * 2048 + xo);
#pragma unroll
            for (int mi = 0; mi < 2; ++mi)
#pragma unroll
                for (int ni = 0; ni < 2; ++ni)
                    acc[mi][ni] = __builtin_amdgcn_mfma_f32_16x16x32_bf16(af[mi], bfr[ni], acc[mi][ni], 0, 0, 0);
        }
        __builtin_amdgcn_sched_barrier(0);
        __builtin_amdgcn_s_barrier();
    }

#pragma unroll
    for (int mi = 0; mi < 2; ++mi) {
        int rowG = tm * 64 + wm * 32 + mi * 16 + q * 4;
#pragma unroll
        for (int ni = 0; ni < 2; ++ni) {
            int colG = tn * 64 + wn * 32 + ni * 16 + c;
            float bv = bias[colG];
#pragma unroll
            for (int r = 0; r < 4; ++r)
                H[(size_t)(rowG + r) * 1024 + colG] = fmaxf(acc[mi][ni][r] + bv, 0.0f);
        }
    }
}

// ---------------- reduce fp32 partials + bias + ReLU -> bf16 ----------------
__global__ __launch_bounds__(256) void reduce_k(const float* __restrict__ P,
                                                const float* __restrict__ bias,
                                                BF16* __restrict__ out,
                                                int S) {
    int i = blockIdx.x * 256 + threadIdx.x;
    float a = bias[i & 1023];
    for (int s = 0; s < S; ++s) a += P[((size_t)s << 20) + i];
    a = fmaxf(a, 0.0f);
    out[i] = __float2bfloat16(a);
}

// ---------------- heads: per-ROI block, cls/bbox dots + softmax + decode ----
// H fp32 [1024][1024] already has bias+ReLU applied.
__global__ __launch_bounds__(256) void head_k(const float* __restrict__ H,
                                              const float* __restrict__ cls_w,
                                              const float* __restrict__ cls_b,
                                              const float* __restrict__ bbox_w,
                                              const float* __restrict__ bbox_b,
                                              const float* __restrict__ boxes,
                                              float* __restrict__ out) {
    __shared__ float red[4][10];
    int roi = blockIdx.x;
    int t = threadIdx.x, w = t >> 6, l = t & 63;
    int k4 = t * 4;

    floatx4 h = *(const floatx4*)(H + (size_t)roi * 1024 + k4);

    float acc[10];
#pragma unroll
    for (int j = 0; j < 10; ++j) acc[j] = 0.0f;
    floatx4 c0 = *(const floatx4*)(cls_w + k4 * 2);
    floatx4 c1 = *(const floatx4*)(cls_w + k4 * 2 + 4);
    acc[0] = h.x * c0.x + h.y * c0.z + h.z * c1.x + h.w * c1.z;
    acc[1] = h.x * c0.y + h.y * c0.w + h.z * c1.y + h.w * c1.w;
    const float* bw = bbox_w + k4 * 8;
#pragma unroll
    for (int kk = 0; kk < 4; ++kk) {
        float hv = (kk == 0) ? h.x : (kk == 1) ? h.y : (kk == 2) ? h.z : h.w;
        floatx4 b0 = *(const floatx4*)(bw + kk * 8);
        floatx4 b1 = *(const floatx4*)(bw + kk * 8 + 4);
        acc[2] += hv * b0.x; acc[3] += hv * b0.y; acc[4] += hv * b0.z; acc[5] += hv * b0.w;
        acc[6] += hv * b1.x; acc[7] += hv * b1.y; acc[8] += hv * b1.z; acc[9] += hv * b1.w;
    }
#pragma unroll
    for (int j = 0; j < 10; ++j) {
#pragma unroll
        for (int off = 32; off > 0; off >>= 1) acc[j] += __shfl_down(acc[j], off);
    }
    if (l == 0) {
#pragma unroll
        for (int j = 0; j < 10; ++j) red[w][j] = acc[j];
    }
    __syncthreads();
    if (t == 0) {
        float f[10];
#pragma unroll
        for (int j = 0; j < 10; ++j) f[j] = red[0][j] + red[1][j] + red[2][j] + red[3][j];
        float s0 = f[0] + cls_b[0], s1 = f[1] + cls_b[1];
        float m = fmaxf(s0, s1);
        float e0 = expf(s0 - m), e1 = expf(s1 - m);
        float inv = 1.0f / (e0 + e1);

        float bx1 = boxes[roi * 4 + 0], by1 = boxes[roi * 4 + 1];
        float bx2 = boxes[roi * 4 + 2], by2 = boxes[roi * 4 + 3];
        float pw = bx2 - bx1, ph = by2 - by1;
        float cx = bx1 + 0.5f * pw, cy = by1 + 0.5f * ph;
        const float CLAMPV = 4.135166556742356f;
        float* orow = out + roi * 10;
#pragma unroll
        for (int cl = 0; cl < 2; ++cl) {
            float dx = (f[2 + cl * 4 + 0] + bbox_b[cl * 4 + 0]) * 0.1f;
            float dy = (f[2 + cl * 4 + 1] + bbox_b[cl * 4 + 1]) * 0.1f;
            float dw = fminf((f[2 + cl * 4 + 2] + bbox_b[cl * 4 + 2]) * 0.2f, CLAMPV);
            float dh = fminf((f[2 + cl * 4 + 3] + bbox_b[cl * 4 + 3]) * 0.2f, CLAMPV);
            float pcx = dx * pw + cx, pcy = dy * ph + cy;
            float pww = expf(dw) * pw, phh = expf(dh) * ph;
            orow[cl * 4 + 0] = fminf(fmaxf(pcx - 0.5f * pww, 0.0f), 1088.0f);
            orow[cl * 4 + 1] = fminf(fmaxf(pcy - 0.5f * phh, 0.0f), 800.0f);
            orow[cl * 4 + 2] = fminf(fmaxf(pcx + 0.5f * pww, 0.0f), 1088.0f);
            orow[cl * 4 + 3] = fminf(fmaxf(pcy + 0.5f * phh, 0.0f), 800.0f);
        }
        orow[8] = e0 * inv;
        orow[9] = e1 * inv;
    }
}

extern "C" void kernel_launch(void* const* d_in, const int* in_sizes, int n_in,
                              void* d_out, int out_size, void* d_ws, size_t ws_size,
                              hipStream_t stream) {
    const float* features = (const float*)d_in[0];
    const float* boxes    = (const float*)d_in[1];
    const int*   roi_b    = (const int*)d_in[2];
    const float* fc1_w    = (const float*)d_in[3];
    const float* fc1_b    = (const float*)d_in[4];
    const float* fc2_w    = (const float*)d_in[5];
    const float* fc2_b    = (const float*)d_in[6];
    const float* cls_w    = (const float*)d_in[7];
    const float* cls_b    = (const float*)d_in[8];
    const float* bbox_w   = (const float*)d_in[9];
    const float* bbox_b   = (const float*)d_in[10];
    float* out = (float*)d_out;

    char* ws = (char*)d_ws;
    BF16* featT = (BF16*)(ws + 0);           // [0, 13,926,400)
    BF16* w1t   = (BF16*)(ws + 13926400);    // [.., 39,616,512)
    BF16* w2t   = (BF16*)(ws + 39616512);    // [.., 41,713,664)
    BF16* feats = (BF16*)(ws + 41713664);    // [.., 67,403,776)
    BF16* h1    = (BF16*)(ws + 67403776);    // [.., 69,500,928)
    float* P1   = (float*)(ws + 69500928);   // 7 * 4 MB -> ends 98,861,056 (ws = 256 MiB)
    float* H2   = (float*)(ws + 0);          // 4 MB fp32; reuses dead featT region

    int S1 = 7;   // 12544 = 7 * 1792, 1792 = 28 * 64

    t_feat<<<3400, 256, 0, stream>>>(features, featT);

    // roi blocks 0..1023 first; at 8 blocks/CU, 1024 roi + 1024 wt co-resident.
    roi_and_wt<<<7808, 256, 0, stream>>>(featT, boxes, roi_b, feats,
                                         fc1_w, fc2_w, w1t, w2t);

    gemm_splitk<<<64 * S1, 256, 0, stream>>>(feats, w1t, P1, 12544, 12544 / S1);
    reduce_k<<<4096, 256, 0, stream>>>(P1, fc1_b, h1, S1);

    gemm_fc2<<<256, 256, 0, stream>>>(h1, w2t, fc2_b, H2);

    head_k<<<1000, 256, 0, stream>>>(H2, cls_w, cls_b, bbox_w, bbox_b, boxes, out);
}

// Round 11
// 203.533 us; speedup vs baseline: 1.0043x; 1.0043x over previous
//
#include <hip/hip_runtime.h>
#include <hip/hip_bf16.h>

#define BF16 __hip_bfloat16

typedef __bf16 bf16x8 __attribute__((ext_vector_type(8)));
typedef float floatx4 __attribute__((ext_vector_type(4)));

typedef const __attribute__((address_space(1))) void GV;
typedef __attribute__((address_space(3))) void LV;
// async global->LDS, 16B per lane; LDS dest must be wave-uniform base + lane*16
#define GLD16(gp, lp) __builtin_amdgcn_global_load_lds((GV*)(gp), (LV*)(lp), 16, 0, 0)

// ---------------- features transpose + fp32->bf16 (roi_align's only dep) ----
__global__ __launch_bounds__(256) void t_feat(const float* __restrict__ features,
                                              BF16* __restrict__ featT) {
    __shared__ float tile[64][33];
    int bid = blockIdx.x;                   // 2 x [256][13600]: 4 x 425 tiles each
    int z = bid / 1700, r = bid - z * 1700;
    int cx = r % 425, cy = r / 425;
    const int R = 256, C = 13600;
    const float* ip = features + (size_t)z * 256 * 13600;
    BF16* op = featT + (size_t)z * 256 * 13600;

    int tx = threadIdx.x & 31, ty = threadIdx.x >> 5;
    int r0 = cy << 6, c0 = cx << 5;
#pragma unroll
    for (int i = 0; i < 8; ++i)
        tile[ty + i * 8][tx] = ip[(size_t)(r0 + ty + i * 8) * C + c0 + tx];
    __syncthreads();
#pragma unroll
    for (int i = 0; i < 4; ++i) {
        int c = ty + i * 8;
        BF16 a = __float2bfloat16(tile[tx * 2][c]);       // 2-way LDS alias: free
        BF16 b = __float2bfloat16(tile[tx * 2 + 1][c]);
        unsigned int pk = (unsigned int)*(unsigned short*)&a |
                          ((unsigned int)*(unsigned short*)&b << 16);
        *(unsigned int*)(op + (size_t)(c0 + c) * R + r0 + tx * 2) = pk;
    }
}

// ---------------- ROI align MERGED with weight transposes (round-9 proven) ----
// blocks 0..1023: ROI align; blocks 1024..7807: wt transposes. ROI first, all
// resident. CLOSED: r6/r8/r10 show ROI phase is VMEM-return-bound at ~33%
// occupancy regardless of blocks/CU or wt co-residency — structural floor.
__global__ __launch_bounds__(256) void roi_and_wt(const BF16* __restrict__ featT,
                                                  const float* __restrict__ boxes,
                                                  const int* __restrict__ roi_batch,
                                                  BF16* __restrict__ feats,
                                                  const float* __restrict__ fc1_w,
                                                  const float* __restrict__ fc2_w,
                                                  BF16* __restrict__ w1t,
                                                  BF16* __restrict__ w2t) {
    __shared__ __align__(16) char smem[31360];   // union: roi(31360) | transpose(8448)
    int bid = blockIdx.x;
    int t = threadIdx.x;

    if (bid >= 1024) {
        // ---- weight transpose branch (64x32 tile, same as t_feat) ----
        float (*tile)[33] = (float(*)[33])smem;
        int r = bid - 1024;
        const float* ip;
        BF16* op;
        int R, C, cx, cy;
        if (r < 6272) {                     // fc1_w: [12544][1024], 196 x 32 tiles
            cx = r & 31; cy = r >> 5;
            R = 12544; C = 1024;
            ip = fc1_w; op = w1t;
        } else {                            // fc2_w: [1024][1024], 16 x 32 tiles
            r -= 6272;
            cx = r & 31; cy = r >> 5;
            R = 1024; C = 1024;
            ip = fc2_w; op = w2t;
        }
        int tx = t & 31, ty = t >> 5;
        int r0 = cy << 6, c0 = cx << 5;
#pragma unroll
        for (int i = 0; i < 8; ++i)
            tile[ty + i * 8][tx] = ip[(size_t)(r0 + ty + i * 8) * C + c0 + tx];
        __syncthreads();
#pragma unroll
        for (int i = 0; i < 4; ++i) {
            int c = ty + i * 8;
            BF16 a = __float2bfloat16(tile[tx * 2][c]);
            BF16 b = __float2bfloat16(tile[tx * 2 + 1][c]);
            unsigned int pk = (unsigned int)*(unsigned short*)&a |
                              ((unsigned int)*(unsigned short*)&b << 16);
            *(unsigned int*)(op + (size_t)(c0 + c) * R + r0 + tx * 2) = pk;
        }
        return;
    }

    // ---- ROI align branch ----
    int   (*s_off)[4] = (int(*)[4])smem;            // [196][4] = 3136 B
    float (*s_w)[4]   = (float(*)[4])(smem + 3136); // [196][4] = 3136 B
    BF16* lbuf        = (BF16*)(smem + 6272);       // 12544 bf16 = 25088 B

    int roi = bid;
    BF16* orow = feats + (size_t)roi * 12544;
    if (roi >= 1000) {
        uint4* o4 = (uint4*)orow;
        uint4 z = {0u, 0u, 0u, 0u};
        for (int i = t; i < 1568; i += 256) o4[i] = z;
        return;
    }
    int b = roi_batch[roi];

    if (t < 196) {
        float x1 = boxes[roi * 4 + 0] * 0.125f;
        float y1 = boxes[roi * 4 + 1] * 0.125f;
        float x2 = boxes[roi * 4 + 2] * 0.125f;
        float y2 = boxes[roi * 4 + 3] * 0.125f;
        float bw = fmaxf(x2 - x1, 1.0f) * (1.0f / 7.0f);
        float bh = fmaxf(y2 - y1, 1.0f) * (1.0f / 7.0f);
        int cell = t >> 2, s = t & 3;
        int oy = cell / 7, ox = cell - oy * 7;
        int sy = s >> 1, sx = s & 1;
        float yc = y1 + ((float)oy + ((float)sy + 0.5f) * 0.5f) * bh;
        float xc = x1 + ((float)ox + ((float)sx + 0.5f) * 0.5f) * bw;
        yc = fminf(fmaxf(yc, 0.0f), 99.0f);
        xc = fminf(fmaxf(xc, 0.0f), 135.0f);
        float y0f = floorf(yc), x0f = floorf(xc);
        int y0 = (int)y0f, x0 = (int)x0f;
        int y1i = min(y0 + 1, 99), x1i = min(x0 + 1, 135);
        float ly = yc - y0f, lx = xc - x0f;
        s_w[t][0] = (1.0f - ly) * (1.0f - lx) * 0.25f;
        s_w[t][1] = (1.0f - ly) * lx * 0.25f;
        s_w[t][2] = ly * (1.0f - lx) * 0.25f;
        s_w[t][3] = ly * lx * 0.25f;
        s_off[t][0] = (y0 * 136 + x0) * 256;
        s_off[t][1] = (y0 * 136 + x1i) * 256;
        s_off[t][2] = (y1i * 136 + x0) * 256;
        s_off[t][3] = (y1i * 136 + x1i) * 256;
    }
    __syncthreads();

    int cb = t & 31, g = t >> 5;   // ch = cb*8..cb*8+7; cell group g (8 groups)
    const BF16* fb = featT + (size_t)b * (100 * 136 * 256) + cb * 8;
    int chbase = cb * 8;
    for (int cell = g; cell < 49; cell += 8) {
        float a[8];
#pragma unroll
        for (int j = 0; j < 8; ++j) a[j] = 0.0f;
#pragma unroll
        for (int s = 0; s < 4; ++s) {
            int p = cell * 4 + s;
#pragma unroll
            for (int tap = 0; tap < 4; ++tap) {
                float w = s_w[p][tap];
                bf16x8 v = *(const bf16x8*)(fb + s_off[p][tap]);
#pragma unroll
                for (int j = 0; j < 8; ++j) a[j] += w * (float)v[j];
            }
        }
#pragma unroll
        for (int j = 0; j < 8; ++j)
            lbuf[(chbase + j) * 49 + cell] = __float2bfloat16(a[j]);
    }
    __syncthreads();
    uint4* o4 = (uint4*)orow;
    const uint4* l4 = (const uint4*)lbuf;
    for (int i = t; i < 1568; i += 256) o4[i] = l4[i];
}

// ---- split-K bf16 MFMA GEMM, 128x128 tile, BK=64, S=8 UNEQUAL chunks ----
// 2-buffer (64 KiB) counted-vmcnt pipeline (round-5 proven). XCD-chunked
// swizzle (proved FETCH 113 -> 50 MB). 512 blocks = exactly 2 blocks/CU
// (448 left 64 CUs half-idle: makespan 2T with 12.5% waste). 12544 =
// 6*1600 + 2*1472, both % 64 == 0: slabs 0..5 get 1600, slabs 6..7 get 1472.
#define STAGE_TILE(kbi, bj)                                                     \
    do {                                                                        \
        size_t ko_ = (size_t)(kbi) * 128;                                       \
        _Pragma("unroll")                                                       \
        for (int i_ = 0; i_ < 4; ++i_) {                                        \
            GLD16(gA + (size_t)(i_ * 8) * strideA + ko_,                        \
                  &lds[bj][0][lw + i_ * 1024]);                                 \
            GLD16(gB + (size_t)(i_ * 8) * strideA + ko_,                        \
                  &lds[bj][1][lw + i_ * 1024]);                                 \
        }                                                                       \
    } while (0)

__global__ __launch_bounds__(256) void gemm_splitk(const BF16* __restrict__ A,
                                                   const BF16* __restrict__ Bt,
                                                   float* __restrict__ P) {
    __shared__ char lds[2][2][16384];   // 64 KB: 2 buffers x (A,B)
    int b = blockIdx.x;
    int L = (b & 7) * 64 + (b >> 3);    // XCD-chunked, bijective (512 % 8 == 0)
    int tn = L & 7, tm = (L >> 3) & 7, s = L >> 6;   // s in [0,8)

    int w = threadIdx.x >> 6, l = threadIdx.x & 63;
    int wm = w & 1, wn = w >> 1;
    int chunk = (s < 6) ? 1600 : 1472;
    int k0 = (s < 6) ? s * 1600 : 9600 + (s - 6) * 1472;

    floatx4 acc[4][4];
#pragma unroll
    for (int i = 0; i < 4; ++i)
#pragma unroll
        for (int j = 0; j < 4; ++j) acc[i][j] = (floatx4){0.f, 0.f, 0.f, 0.f};

    const size_t strideA = (size_t)12544 * 2;
    int r8 = l >> 3;
    int g8 = (l & 7) ^ r8;       // XOR-swizzled global chunk for this lane
    const char* gA = (const char*)A + (size_t)(tm * 128 + w * 32 + r8) * strideA
                     + (size_t)k0 * 2 + (size_t)g8 * 16;
    const char* gB = (const char*)Bt + (size_t)(tn * 128 + w * 32 + r8) * strideA
                     + (size_t)k0 * 2 + (size_t)g8 * 16;
    int lw = w * 4096 + l * 16;  // wave-uniform base + l*16: gload_lds layout

    int c = l & 15, q = l >> 4;
    int xa0 = ((0 * 4 + q) ^ (c & 7)) * 16;
    int xa1 = ((1 * 4 + q) ^ (c & 7)) * 16;
    int abase = (wm * 64 + c) * 128;
    int bbase = (wn * 64 + c) * 128;

    int nIter = chunk >> 6;      // 25 or 23

    STAGE_TILE(0, 0);

    for (int kb = 0; kb < nIter; ++kb) {
        int cur = kb & 1;
        if (kb + 1 < nIter) {
            STAGE_TILE(kb + 1, cur ^ 1);   // ordered after prev reads by barrier #2
            asm volatile("s_waitcnt vmcnt(8)" ::: "memory");   // stage(kb) landed
        } else {
            asm volatile("s_waitcnt vmcnt(0)" ::: "memory");
        }
        __builtin_amdgcn_sched_barrier(0);
        __builtin_amdgcn_s_barrier();      // all waves' stage(kb) landed
        __builtin_amdgcn_sched_barrier(0);

        const char* bufA = lds[cur][0];
        const char* bufB = lds[cur][1];
#pragma unroll
        for (int kk = 0; kk < 2; ++kk) {
            int xo = kk ? xa1 : xa0;
            bf16x8 af[4], bfr[4];
#pragma unroll
            for (int mi = 0; mi < 4; ++mi) af[mi] = *(const bf16x8*)(bufA + abase + mi * 2048 + xo);
#pragma unroll
            for (int ni = 0; ni < 4; ++ni) bfr[ni] = *(const bf16x8*)(bufB + bbase + ni * 2048 + xo);
#pragma unroll
            for (int mi = 0; mi < 4; ++mi)
#pragma unroll
                for (int ni = 0; ni < 4; ++ni)
                    acc[mi][ni] = __builtin_amdgcn_mfma_f32_16x16x32_bf16(af[mi], bfr[ni], acc[mi][ni], 0, 0, 0);
        }
        __builtin_amdgcn_sched_barrier(0);
        __builtin_amdgcn_s_barrier();      // reads of buf[cur] done before restage
    }

    size_t base = (size_t)s << 20;
#pragma unroll
    for (int mi = 0; mi < 4; ++mi) {
        int rowG = tm * 128 + wm * 64 + mi * 16 + q * 4;
#pragma unroll
        for (int ni = 0; ni < 4; ++ni) {
            int colG = tn * 128 + wn * 64 + ni * 16 + c;
#pragma unroll
            for (int r = 0; r < 4; ++r)
                P[base + (size_t)(rowG + r) * 1024 + colG] = acc[mi][ni][r];
        }
    }
}

// ---- fc2 GEMM: 64x64 tile, full K=1024, 256 blocks (1/CU), bias+ReLU ----
// (round-9 proven: +4-6us vs 64-block version)
#define STAGE64(kbi, bj)                                                        \
    do {                                                                        \
        size_t ko_ = (size_t)(kbi) * 128;                                       \
        _Pragma("unroll")                                                       \
        for (int i_ = 0; i_ < 2; ++i_) {                                        \
            GLD16(gA + (size_t)(i_ * 8) * strideA + ko_,                        \
                  &lds[bj][0][lw64 + i_ * 1024]);                               \
            GLD16(gB + (size_t)(i_ * 8) * strideA + ko_,                        \
                  &lds[bj][1][lw64 + i_ * 1024]);                               \
        }                                                                       \
    } while (0)

__global__ __launch_bounds__(256) void gemm_fc2(const BF16* __restrict__ A,
                                                const BF16* __restrict__ Bt,
                                                const float* __restrict__ bias,
                                                float* __restrict__ H) {
    __shared__ char lds[2][2][8192];    // 32 KB: 2 bufs x (A 64x64, B 64x64)
    int b = blockIdx.x;
    int L = (b & 7) * 32 + (b >> 3);    // XCD-chunked, 256 % 8 == 0
    int tn = L & 15, tm = L >> 4;       // 16 x 16 tiles of 64x64

    int w = threadIdx.x >> 6, l = threadIdx.x & 63;
    int wm = w & 1, wn = w >> 1;        // wave quadrant: 32x32 out each

    floatx4 acc[2][2];
#pragma unroll
    for (int i = 0; i < 2; ++i)
#pragma unroll
        for (int j = 0; j < 2; ++j) acc[i][j] = (floatx4){0.f, 0.f, 0.f, 0.f};

    const size_t strideA = 2048;   // K=1024 bf16
    int r8 = l >> 3;
    int g8 = (l & 7) ^ r8;         // XOR swizzle on global source chunk
    const char* gA = (const char*)A + (size_t)(tm * 64 + w * 16 + r8) * strideA
                     + (size_t)g8 * 16;
    const char* gB = (const char*)Bt + (size_t)(tn * 64 + w * 16 + r8) * strideA
                     + (size_t)g8 * 16;
    int lw64 = w * 2048 + l * 16;

    int c = l & 15, q = l >> 4;
    int xa0 = ((0 * 4 + q) ^ (c & 7)) * 16;
    int xa1 = ((1 * 4 + q) ^ (c & 7)) * 16;
    int abase = (wm * 32 + c) * 128;
    int bbase = (wn * 32 + c) * 128;

    const int nIter = 16;   // 1024 / 64

    STAGE64(0, 0);

    for (int kb = 0; kb < nIter; ++kb) {
        int cur = kb & 1;
        if (kb + 1 < nIter) {
            STAGE64(kb + 1, cur ^ 1);
            asm volatile("s_waitcnt vmcnt(4)" ::: "memory");   // stage(kb) landed
        } else {
            asm volatile("s_waitcnt vmcnt(0)" ::: "memory");
        }
        __builtin_amdgcn_sched_barrier(0);
        __builtin_amdgcn_s_barrier();
        __builtin_amdgcn_sched_barrier(0);

        const char* bufA = lds[cur][0];
        const char* bufB = lds[cur][1];
#pragma unroll
        for (int kk = 0; kk < 2; ++kk) {
            int xo = kk ? xa1 : xa0;
            bf16x8 af[2], bfr[2];
#pragma unroll
            for (int mi = 0; mi < 2; ++mi) af[mi] = *(const bf16x8*)(bufA + abase + mi * 2048 + xo);
#pragma unroll
            for (int ni = 0; ni < 2; ++ni) bfr[ni] = *(const bf16x8*)(bufB + bbase + ni * 2048 + xo);
#pragma unroll
            for (int mi = 0; mi < 2; ++mi)
#pragma unroll
                for (int ni = 0; ni < 2; ++ni)
                    acc[mi][ni] = __builtin_amdgcn_mfma_f32_16x16x32_bf16(af[mi], bfr[ni], acc[mi][ni], 0, 0, 0);
        }
        __builtin_amdgcn_sched_barrier(0);
        __builtin_amdgcn_s_barrier();
    }

#pragma unroll
    for (int mi = 0; mi < 2; ++mi) {
        int rowG = tm * 64 + wm * 32 + mi * 16 + q * 4;
#pragma unroll
        for (int ni = 0; ni < 2; ++ni) {
            int colG = tn * 64 + wn * 32 + ni * 16 + c;
            float bv = bias[colG];
#pragma unroll
            for (int r = 0; r < 4; ++r)
                H[(size_t)(rowG + r) * 1024 + colG] = fmaxf(acc[mi][ni][r] + bv, 0.0f);
        }
    }
}

// ------- reduce fp32 partials (S=8) + bias + ReLU -> bf16, float4/lane -------
// 1024 blocks x 256 threads x 4 elems = 1,048,576 elements.
__global__ __launch_bounds__(256) void reduce_k(const float* __restrict__ P,
                                                const float* __restrict__ bias,
                                                BF16* __restrict__ out) {
    int i4 = (blockIdx.x * 256 + threadIdx.x) * 4;
    floatx4 a = *(const floatx4*)(bias + (i4 & 1023));
#pragma unroll
    for (int s = 0; s < 8; ++s) {
        floatx4 p = *(const floatx4*)(P + ((size_t)s << 20) + i4);
        a.x += p.x; a.y += p.y; a.z += p.z; a.w += p.w;
    }
    BF16 o0 = __float2bfloat16(fmaxf(a.x, 0.0f));
    BF16 o1 = __float2bfloat16(fmaxf(a.y, 0.0f));
    BF16 o2 = __float2bfloat16(fmaxf(a.z, 0.0f));
    BF16 o3 = __float2bfloat16(fmaxf(a.w, 0.0f));
    unsigned long long pk = (unsigned long long)*(unsigned short*)&o0
                          | ((unsigned long long)*(unsigned short*)&o1 << 16)
                          | ((unsigned long long)*(unsigned short*)&o2 << 32)
                          | ((unsigned long long)*(unsigned short*)&o3 << 48);
    *(unsigned long long*)(out + i4) = pk;
}

// ---------------- heads: per-ROI block, cls/bbox dots + softmax + decode ----
// H fp32 [1024][1024] already has bias+ReLU applied.
__global__ __launch_bounds__(256) void head_k(const float* __restrict__ H,
                                              const float* __restrict__ cls_w,
                                              const float* __restrict__ cls_b,
                                              const float* __restrict__ bbox_w,
                                              const float* __restrict__ bbox_b,
                                              const float* __restrict__ boxes,
                                              float* __restrict__ out) {
    __shared__ float red[4][10];
    int roi = blockIdx.x;
    int t = threadIdx.x, w = t >> 6, l = t & 63;
    int k4 = t * 4;

    floatx4 h = *(const floatx4*)(H + (size_t)roi * 1024 + k4);

    float acc[10];
#pragma unroll
    for (int j = 0; j < 10; ++j) acc[j] = 0.0f;
    floatx4 c0 = *(const floatx4*)(cls_w + k4 * 2);
    floatx4 c1 = *(const floatx4*)(cls_w + k4 * 2 + 4);
    acc[0] = h.x * c0.x + h.y * c0.z + h.z * c1.x + h.w * c1.z;
    acc[1] = h.x * c0.y + h.y * c0.w + h.z * c1.y + h.w * c1.w;
    const float* bw = bbox_w + k4 * 8;
#pragma unroll
    for (int kk = 0; kk < 4; ++kk) {
        float hv = (kk == 0) ? h.x : (kk == 1) ? h.y : (kk == 2) ? h.z : h.w;
        floatx4 b0 = *(const floatx4*)(bw + kk * 8);
        floatx4 b1 = *(const floatx4*)(bw + kk * 8 + 4);
        acc[2] += hv * b0.x; acc[3] += hv * b0.y; acc[4] += hv * b0.z; acc[5] += hv * b0.w;
        acc[6] += hv * b1.x; acc[7] += hv * b1.y; acc[8] += hv * b1.z; acc[9] += hv * b1.w;
    }
#pragma unroll
    for (int j = 0; j < 10; ++j) {
#pragma unroll
        for (int off = 32; off > 0; off >>= 1) acc[j] += __shfl_down(acc[j], off);
    }
    if (l == 0) {
#pragma unroll
        for (int j = 0; j < 10; ++j) red[w][j] = acc[j];
    }
    __syncthreads();
    if (t == 0) {
        float f[10];
#pragma unroll
        for (int j = 0; j < 10; ++j) f[j] = red[0][j] + red[1][j] + red[2][j] + red[3][j];
        float s0 = f[0] + cls_b[0], s1 = f[1] + cls_b[1];
        float m = fmaxf(s0, s1);
        float e0 = expf(s0 - m), e1 = expf(s1 - m);
        float inv = 1.0f / (e0 + e1);

        float bx1 = boxes[roi * 4 + 0], by1 = boxes[roi * 4 + 1];
        float bx2 = boxes[roi * 4 + 2], by2 = boxes[roi * 4 + 3];
        float pw = bx2 - bx1, ph = by2 - by1;
        float cx = bx1 + 0.5f * pw, cy = by1 + 0.5f * ph;
        const float CLAMPV = 4.135166556742356f;
        float* orow = out + roi * 10;
#pragma unroll
        for (int cl = 0; cl < 2; ++cl) {
            float dx = (f[2 + cl * 4 + 0] + bbox_b[cl * 4 + 0]) * 0.1f;
            float dy = (f[2 + cl * 4 + 1] + bbox_b[cl * 4 + 1]) * 0.1f;
            float dw = fminf((f[2 + cl * 4 + 2] + bbox_b[cl * 4 + 2]) * 0.2f, CLAMPV);
            float dh = fminf((f[2 + cl * 4 + 3] + bbox_b[cl * 4 + 3]) * 0.2f, CLAMPV);
            float pcx = dx * pw + cx, pcy = dy * ph + cy;
            float pww = expf(dw) * pw, phh = expf(dh) * ph;
            orow[cl * 4 + 0] = fminf(fmaxf(pcx - 0.5f * pww, 0.0f), 1088.0f);
            orow[cl * 4 + 1] = fminf(fmaxf(pcy - 0.5f * phh, 0.0f), 800.0f);
            orow[cl * 4 + 2] = fminf(fmaxf(pcx + 0.5f * pww, 0.0f), 1088.0f);
            orow[cl * 4 + 3] = fminf(fmaxf(pcy + 0.5f * phh, 0.0f), 800.0f);
        }
        orow[8] = e0 * inv;
        orow[9] = e1 * inv;
    }
}

extern "C" void kernel_launch(void* const* d_in, const int* in_sizes, int n_in,
                              void* d_out, int out_size, void* d_ws, size_t ws_size,
                              hipStream_t stream) {
    const float* features = (const float*)d_in[0];
    const float* boxes    = (const float*)d_in[1];
    const int*   roi_b    = (const int*)d_in[2];
    const float* fc1_w    = (const float*)d_in[3];
    const float* fc1_b    = (const float*)d_in[4];
    const float* fc2_w    = (const float*)d_in[5];
    const float* fc2_b    = (const float*)d_in[6];
    const float* cls_w    = (const float*)d_in[7];
    const float* cls_b    = (const float*)d_in[8];
    const float* bbox_w   = (const float*)d_in[9];
    const float* bbox_b   = (const float*)d_in[10];
    float* out = (float*)d_out;

    char* ws = (char*)d_ws;
    BF16* featT = (BF16*)(ws + 0);           // [0, 13,926,400)
    BF16* w1t   = (BF16*)(ws + 13926400);    // [.., 39,616,512)
    BF16* w2t   = (BF16*)(ws + 39616512);    // [.., 41,713,664)
    BF16* feats = (BF16*)(ws + 41713664);    // [.., 67,403,776)
    BF16* h1    = (BF16*)(ws + 67403776);    // [.., 69,500,928)
    float* P1   = (float*)(ws + 69500928);   // 8 * 4 MB -> ends 103,055,360 (ws = 256 MiB)
    float* H2   = (float*)(ws + 0);          // 4 MB fp32; reuses dead featT region

    t_feat<<<3400, 256, 0, stream>>>(features, featT);

    // roi blocks 0..1023 first (all resident); wt blocks 1024..7807 stream in.
    roi_and_wt<<<7808, 256, 0, stream>>>(featT, boxes, roi_b, feats,
                                         fc1_w, fc2_w, w1t, w2t);

    gemm_splitk<<<512, 256, 0, stream>>>(feats, w1t, P1);   // S=8, 2 blocks/CU
    reduce_k<<<1024, 256, 0, stream>>>(P1, fc1_b, h1);

    gemm_fc2<<<256, 256, 0, stream>>>(h1, w2t, fc2_b, H2);

    head_k<<<1000, 256, 0, stream>>>(H2, cls_w, cls_b, bbox_w, bbox_b, boxes, out);
}